// Round 1
// 310.633 us; speedup vs baseline: 1.0728x; 1.0728x over previous
//
#include <hip/hip_runtime.h>

// Centroids: argmin_c ||latent[r] - coords[c]||^2, 131072 rows x 2048 coords, D=128.
//
// prep_coords: coords -> bf16 hi/lo "B images", XOR-swizzled granules (contiguous
//   LDS copy AND conflict-free frag ds_read_b128), + c2, + counter=0.
// centroid_fast (this round's rewrite):
//   - 64-row waves (mt=0..3): each LDS B-fragment feeds 4 MFMAs per pass instead
//     of 2 -> LDS read cycles/chunk halve (3072 vs MFMA 6144 per CU). R6's spill
//     is avoided by __launch_bounds__(256,2): A frags 128 VGPR + state 48 fits 256.
//   - double-buffered LDS B (2x32KB) staged with global_load_lds width=16,
//     counted s_waitcnt vmcnt(8) + raw s_barrier (2-phase template): next chunk's
//     loads stay in flight across the barrier, never drained mid-loop.
//   - c2 folded into MFMA acc init (acc = -0.5*c2, track argmax): no per-slot
//     fmaf, no in-loop global loads (c2 table lives in LDS, loaded once).
//     Scores are half-scale -> MARGIN_H = 0.01 (== 0.02 full-scale, unchanged).
// refine_fp64: rows with gap < margin recomputed exactly in fp64 (~0.5%);
//   4 independent accumulators break the dependent fp64 fma chain.
//
// ws layout (bytes): 0 c2 | 8192 counter | 16384 worklist(128KB) |
//                    262144 Bh (512KB) | 786432 Bl (512KB) | end 1310720

constexpr int D = 128;
constexpr int C = 2048;
constexpr int NCH = 64;            // coords per chunk
constexpr int NCHUNKS = C / NCH;   // 32
constexpr float MARGIN_H = 0.01f;  // half-scale: bf16x2 err ~2.5e-3 -> 4x headroom
constexpr int WL_CAP = 32768;

constexpr size_t WS_CNT = 8192;
constexpr size_t WS_WL  = 16384;
constexpr size_t WS_BH  = 262144;
constexpr size_t WS_BL  = 786432;

typedef __attribute__((ext_vector_type(8))) short short8;
typedef __attribute__((ext_vector_type(4))) float f32x4;
typedef unsigned int u32;

__device__ inline unsigned short bf16_rne(float x) {
    unsigned u = __float_as_uint(x);
    u += 0x7FFFu + ((u >> 16) & 1u);
    return (unsigned short)(u >> 16);
}
__device__ inline float bf16_to_f(unsigned short h) {
    return __uint_as_float(((unsigned)h) << 16);
}
__device__ inline void split8(const float* v, short8* hi, short8* lo) {
#pragma unroll
    for (int j = 0; j < 8; ++j) {
        unsigned short h = bf16_rne(v[j]);
        (*hi)[j] = (short)h;
        (*lo)[j] = (short)bf16_rne(v[j] - bf16_to_f(h));
    }
}

// async global->LDS, 16B per lane. LDS dest must be wave-uniform base + lane*16,
// which our tid*16-contiguous layout satisfies.
__device__ __forceinline__ void gl_lds16(const void* g, void* l) {
    __builtin_amdgcn_global_load_lds(
        (const __attribute__((address_space(1))) u32*)g,
        (__attribute__((address_space(3))) u32*)l, 16, 0, 0);
}

// ---------------- prep: B images + c2 ----------------
// 32768 threads: thread t -> coord c = t>>4, k-granule k8 = t&15.
// Image: chunk ch = c>>6, nl = c&63; granule g = nl*16 + (k8 ^ (nl&15)).
__global__ void prep_coords(const float* __restrict__ coords,
                            unsigned short* __restrict__ Bh,
                            unsigned short* __restrict__ Bl,
                            float* __restrict__ c2, int* __restrict__ counter) {
    int t = blockIdx.x * blockDim.x + threadIdx.x;
    if (t == 0) *counter = 0;
    if (t >= C * 16) return;
    int c  = t >> 4;
    int k8 = t & 15;
    float v[8];
    *(float4*)(v)     = *(const float4*)(coords + (size_t)c * D + k8 * 8);
    *(float4*)(v + 4) = *(const float4*)(coords + (size_t)c * D + k8 * 8 + 4);
    short8 hi, lo;
    split8(v, &hi, &lo);
    int ch = c >> 6, nl = c & 63;
    size_t off = (size_t)ch * (NCH * 128) + ((size_t)nl * 16 + (k8 ^ (nl & 15))) * 8;
    *(short8*)(Bh + off) = hi;
    *(short8*)(Bl + off) = lo;
    float p = 0.f;
#pragma unroll
    for (int j = 0; j < 8; ++j) p = fmaf(v[j], v[j], p);
#pragma unroll
    for (int m = 1; m <= 8; m <<= 1) p += __shfl_xor(p, m, 64);
    if (k8 == 0) c2[c] = p;
}

// ---------------- main kernel ----------------

__global__ __launch_bounds__(256, 2) void centroid_fast(
        const float* __restrict__ latent,
        const unsigned short* __restrict__ Bh_img,
        const unsigned short* __restrict__ Bl_img,
        const float* __restrict__ c2g,
        int* __restrict__ out,
        int* __restrict__ counter,
        int* __restrict__ worklist) {
    // 2x16KB hi + 2x16KB lo (double-buffered) + full c2 table = 72 KB -> 2 blocks/CU
    __shared__ __align__(16) unsigned short Bh[2][NCH * 128], Bl[2][NCH * 128];
    __shared__ __align__(16) float sc2[C];

    const int tid  = threadIdx.x;
    const int wid  = tid >> 6;            // wave 0..3 -> rows wid*64..wid*64+63
    const int lane = tid & 63;
    const int q    = lane >> 4, lr = lane & 15;
    const int row_block = blockIdx.x * 256;

    // ---- prologue: stage chunk 0 (async), c2 table, A fragments ----
    {
        const unsigned short* sh = Bh_img;
        const unsigned short* sl = Bl_img;
#pragma unroll
        for (int i = 0; i < 4; ++i) {
            int e = (i * 256 + tid) * 8;
            gl_lds16(sh + e, &Bh[0][e]);
            gl_lds16(sl + e, &Bl[0][e]);
        }
    }
#pragma unroll
    for (int i = 0; i < 2; ++i) {
        int e = (i * 256 + tid) * 4;
        *(float4*)(sc2 + e) = *(const float4*)(c2g + e);
    }

    // A fragments: lane holds A[m = lr][k = ks*32 + q*8 .. +8] for rows
    // wid*64 + mt*16 + lr. 32 short8 = 128 VGPRs long-lived.
    short8 Ah[4][4], Al[4][4];
#pragma unroll
    for (int mt = 0; mt < 4; ++mt) {
        const float* rp = latent + (size_t)(row_block + wid * 64 + mt * 16 + lr) * D;
#pragma unroll
        for (int ks = 0; ks < 4; ++ks) {
            float v[8];
            *(float4*)(v)     = *(const float4*)(rp + ks * 32 + q * 8);
            *(float4*)(v + 4) = *(const float4*)(rp + ks * 32 + q * 8 + 4);
            split8(v, &Ah[mt][ks], &Al[mt][ks]);
        }
    }

    // argmax state over a = dot - 0.5*c2 (== argmin distance), 16 slots
    float b1[16], b2[16];
    int   bidx[16];
#pragma unroll
    for (int s = 0; s < 16; ++s) { b1[s] = -3.4e38f; b2[s] = -3.4e38f; bidx[s] = 0; }

    __syncthreads();   // full drain: chunk-0 stage + sc2 + A loads all visible

    for (int ch = 0; ch < NCHUNKS; ++ch) {
        const int buf = ch & 1;
        // issue next chunk's stage FIRST, then counted wait on current chunk's 8
        if (ch + 1 < NCHUNKS) {
            const unsigned short* sh = Bh_img + (size_t)(ch + 1) * (NCH * 128);
            const unsigned short* sl = Bl_img + (size_t)(ch + 1) * (NCH * 128);
#pragma unroll
            for (int i = 0; i < 4; ++i) {
                int e = (i * 256 + tid) * 8;
                gl_lds16(sh + e, &Bh[buf ^ 1][e]);
                gl_lds16(sl + e, &Bl[buf ^ 1][e]);
            }
            asm volatile("s_waitcnt vmcnt(8)" ::: "memory");  // cur done, next in flight
        } else {
            asm volatile("s_waitcnt vmcnt(0)" ::: "memory");
        }
        __builtin_amdgcn_s_barrier();

#pragma unroll
        for (int nt = 0; nt < 4; ++nt) {
            const int nl = nt * 16 + lr;
            const float mh = -0.5f * sc2[ch * NCH + nl];
            f32x4 acc[4];
#pragma unroll
            for (int mt = 0; mt < 4; ++mt) acc[mt] = (f32x4){mh, mh, mh, mh};
#pragma unroll
            for (int ks = 0; ks < 4; ++ks) {
                const int xv = ((ks * 4) | q) ^ lr;     // swizzle: conflict-free
                const int e  = nl * 128 + xv * 8;
                short8 bh = *(const short8*)(&Bh[buf][e]);
                short8 bl = *(const short8*)(&Bl[buf][e]);
                // pass-major order: dependent MFMAs on the same acc are 4 apart
#pragma unroll
                for (int mt = 0; mt < 4; ++mt)
                    acc[mt] = __builtin_amdgcn_mfma_f32_16x16x32_bf16(Ah[mt][ks], bh, acc[mt], 0, 0, 0);
#pragma unroll
                for (int mt = 0; mt < 4; ++mt)
                    acc[mt] = __builtin_amdgcn_mfma_f32_16x16x32_bf16(Ah[mt][ks], bl, acc[mt], 0, 0, 0);
#pragma unroll
                for (int mt = 0; mt < 4; ++mt)
                    acc[mt] = __builtin_amdgcn_mfma_f32_16x16x32_bf16(Al[mt][ks], bh, acc[mt], 0, 0, 0);
            }
            const int n_global = ch * NCH + nl;
#pragma unroll
            for (int mt = 0; mt < 4; ++mt)
#pragma unroll
                for (int r = 0; r < 4; ++r) {
                    int slot = mt * 4 + r;
                    float a = acc[mt][r];
                    bool gt  = a > b1[slot];
                    float mn = fminf(a, b1[slot]);
                    b2[slot]   = fmaxf(b2[slot], mn);
                    b1[slot]   = fmaxf(a, b1[slot]);
                    bidx[slot] = gt ? n_global : bidx[slot];
                }
        }
        __builtin_amdgcn_s_barrier();   // all reads of buf done before it's restaged
    }

    // butterfly over the 16 col-residue lanes (max semantics)
#pragma unroll
    for (int m = 1; m <= 8; m <<= 1) {
#pragma unroll
        for (int s = 0; s < 16; ++s) {
            float oa = __shfl_xor(b1[s], m, 64);
            float ob = __shfl_xor(b2[s], m, 64);
            int   oi = __shfl_xor(bidx[s], m, 64);
            float mn = fminf(b1[s], oa);
            b2[s] = fmaxf(fmaxf(b2[s], ob), mn);
            bool take = (oa > b1[s]) || (oa == b1[s] && oi < bidx[s]);
            b1[s]   = take ? oa : b1[s];
            bidx[s] = take ? oi : bidx[s];
        }
    }
    // slot s canonical in lane lr==s; row = wid*64 + (s>>2)*16 + q*4 + (s&3)
#pragma unroll
    for (int s = 0; s < 16; ++s) {
        if (lr == s) {
            int row = row_block + wid * 64 + (s >> 2) * 16 + q * 4 + (s & 3);
            out[row] = bidx[s];
            if (b1[s] - b2[s] < MARGIN_H) {
                int w = atomicAdd(counter, 1);
                if (w < WL_CAP) worklist[w] = row;
            }
        }
    }
}

// ---------------- fp64 refine ----------------

__global__ __launch_bounds__(256) void refine_fp64(
        const float* __restrict__ latent, const float* __restrict__ coords,
        const int* __restrict__ worklist, const int* __restrict__ counter,
        int wl_cap, int* __restrict__ out) {
    __shared__ float  xs[D];
    __shared__ double rv[256];
    __shared__ int    ri[256];

    int n = *counter;
    if (n > wl_cap) n = wl_cap;

    for (int wi = blockIdx.x; wi < n; wi += gridDim.x) {
        int row = worklist[wi];
        if (threadIdx.x < D)
            xs[threadIdx.x] = latent[(size_t)row * D + threadIdx.x];
        __syncthreads();

        double best = 1.0e300;
        int    bix  = 0;
        for (int c = threadIdx.x; c < C; c += 256) {
            const float4* cp = (const float4*)(coords + (size_t)c * D);
            // 4 independent accumulators: breaks the 512-deep dependent fma chain
            double s0 = 0.0, s1 = 0.0, s2 = 0.0, s3 = 0.0;
#pragma unroll 8
            for (int k4 = 0; k4 < 32; ++k4) {
                float4 v = cp[k4];
                double d0 = (double)xs[k4 * 4 + 0] - (double)v.x;
                double d1 = (double)xs[k4 * 4 + 1] - (double)v.y;
                double d2 = (double)xs[k4 * 4 + 2] - (double)v.z;
                double d3 = (double)xs[k4 * 4 + 3] - (double)v.w;
                s0 = fma(d0, d0, s0); s1 = fma(d1, d1, s1);
                s2 = fma(d2, d2, s2); s3 = fma(d3, d3, s3);
            }
            double s = (s0 + s1) + (s2 + s3);
            if (s < best) { best = s; bix = c; }
        }
        rv[threadIdx.x] = best;
        ri[threadIdx.x] = bix;
        __syncthreads();
        for (int off = 128; off > 0; off >>= 1) {
            if (threadIdx.x < off) {
                double ov = rv[threadIdx.x + off];
                int    oi = ri[threadIdx.x + off];
                if (ov < rv[threadIdx.x] ||
                    (ov == rv[threadIdx.x] && oi < ri[threadIdx.x])) {
                    rv[threadIdx.x] = ov;
                    ri[threadIdx.x] = oi;
                }
            }
            __syncthreads();
        }
        if (threadIdx.x == 0) out[row] = ri[0];
        __syncthreads();
    }
}

extern "C" void kernel_launch(void* const* d_in, const int* in_sizes, int n_in,
                              void* d_out, int out_size, void* d_ws, size_t ws_size,
                              hipStream_t stream) {
    const float* latent = (const float*)d_in[0];
    const float* coords = (const float*)d_in[1];
    int*         out    = (int*)d_out;

    char* ws = (char*)d_ws;
    float* c2      = (float*)ws;
    int*   counter = (int*)(ws + WS_CNT);
    int*   wl      = (int*)(ws + WS_WL);
    unsigned short* Bh = (unsigned short*)(ws + WS_BH);
    unsigned short* Bl = (unsigned short*)(ws + WS_BL);
    const int n_rows = in_sizes[0] / D;   // 131072

    prep_coords<<<(C * 16) / 256, 256, 0, stream>>>(coords, Bh, Bl, c2, counter);
    centroid_fast<<<n_rows / 256, 256, 0, stream>>>(latent, Bh, Bl, c2, out,
                                                    counter, wl);
    refine_fp64<<<608, 256, 0, stream>>>(latent, coords, wl, counter, WL_CAP, out);
}